// Round 19
// baseline (1784.237 us; speedup 1.0000x reference)
//
#include <hip/hip_runtime.h>
#include <math.h>

#define D 128
#define T_STEPS 8
#define FEAT 26

typedef short bf16x8 __attribute__((ext_vector_type(8)));
typedef unsigned short u16x8 __attribute__((ext_vector_type(8)));
typedef unsigned short u16x4 __attribute__((ext_vector_type(4)));
typedef float f32x4 __attribute__((ext_vector_type(4)));

__device__ inline unsigned short f2bf(float f) {
    unsigned b = __float_as_uint(f);
    b += 0x7FFFu + ((b >> 16) & 1u);
    return (unsigned short)(b >> 16);
}
__device__ inline float bf2f(unsigned short u) {
    return __uint_as_float(((unsigned)u) << 16);
}

// async global->LDS, 16B per lane; lds dest must be wave-uniform base
__device__ inline void gl_lds16(const void* g, void* l) {
    __builtin_amdgcn_global_load_lds(
        (const __attribute__((address_space(1))) void*)g,
        (__attribute__((address_space(3))) void*)l, 16, 0, 0);
}

// fast sigmoid/tanh via v_exp_f32 (exp2) + v_rcp_f32
__device__ inline float fast_sigmoid(float x) {
    float e = __builtin_amdgcn_exp2f(-1.442695041f * x);
    return __builtin_amdgcn_rcpf(1.0f + e);
}
__device__ inline float fast_tanh(float x) {
    float e = __builtin_amdgcn_exp2f(2.885390082f * x);
    return 1.0f - 2.0f * __builtin_amdgcn_rcpf(1.0f + e);
}

// ---------------------------------------------------------------------------
// fused init (bf16 state)
// ---------------------------------------------------------------------------
__global__ void k_init_dual(unsigned short* __restrict__ ip_state,
                            unsigned short* __restrict__ conn_state,
                            const float* __restrict__ feat, int ni_elems,
                            int total) {
    int i = blockIdx.x * blockDim.x + threadIdx.x;
    if (i < ni_elems) {
        ip_state[i] = 0x3F80;
    } else if (i < total) {
        int j = i - ni_elems;
        int r = j >> 7, d = j & 127;
        conn_state[j] = (d < FEAT) ? f2bf(feat[r * FEAT + d]) : (unsigned short)0;
    }
}

__global__ void k_gbias_dual(const float* __restrict__ bi0, const float* __restrict__ br0,
                             float* __restrict__ cb0,
                             const float* __restrict__ bi1, const float* __restrict__ br1,
                             float* __restrict__ cb1) {
    const float* bi = blockIdx.x ? bi1 : bi0;
    const float* br = blockIdx.x ? br1 : br0;
    float* cb = blockIdx.x ? cb1 : cb0;
    int d = threadIdx.x;
    cb[d] = bi[d] + br[d];
    cb[128 + d] = bi[128 + d] + br[128 + d];
    cb[256 + d] = bi[256 + d];
    cb[384 + d] = br[256 + d];
}

// ---------------------------------------------------------------------------
// weight packs (RTN bf16, direct)
// ---------------------------------------------------------------------------
__global__ void k_pack_pq_dual(const float* __restrict__ Wm1,
                               const float* __restrict__ Wm2,
                               short* __restrict__ WGip, short* __restrict__ WGcn) {
    int id = blockIdx.x * blockDim.x + threadIdx.x;
    if (id < 4 * 16 * 512) {
        int i = id & 7;
        int l = (id >> 3) & 63;
        int rest = id >> 9;
        int q = rest % 16;
        int s = rest / 16;
        int k = s * 32 + (l >> 4) * 8 + i;
        int col = q * 16 + (l & 15);
        float fip = (col < 128) ? Wm1[k * 128 + col] : Wm2[(128 + k) * 128 + (col - 128)];
        float fcn = (col < 128) ? Wm2[k * 128 + col] : Wm1[(128 + k) * 128 + (col - 128)];
        WGip[id] = (short)f2bf(fip);
        WGcn[id] = (short)f2bf(fcn);
    }
}

__global__ void k_pack_gru_dual(const float* __restrict__ K0, const float* __restrict__ RK0,
                                short* __restrict__ WG0,
                                const float* __restrict__ K1, const float* __restrict__ RK1,
                                short* __restrict__ WG1, int nblk0) {
    int total = 8 * 24 * 512;
    bool sec = blockIdx.x >= nblk0;
    const float* K = sec ? K1 : K0;
    const float* RK = sec ? RK1 : RK0;
    short* WG = sec ? WG1 : WG0;
    int id = (sec ? blockIdx.x - nblk0 : blockIdx.x) * blockDim.x + threadIdx.x;
    if (id < total) {
        int i = id & 7;
        int l = (id >> 3) & 63;
        int rest = id >> 9;
        int q = rest % 24;
        int s = rest / 24;
        int ct = (s < 4) ? q : (q < 16 ? q : q + 8);
        int k = s * 32 + (l >> 4) * 8 + i;
        int col = ct * 16 + (l & 15);
        float v = 0.f;
        if (k < 128) {
            if (col < 384) v = K[k * 384 + col];
        } else {
            int kk = k - 128;
            if (col < 256) v = RK[kk * 384 + col];
            else if (col >= 384) v = RK[kk * 384 + (col - 128)];
        }
        WG[id] = (short)f2bf(v);
    }
}

__global__ void k_pack_r1(const float* __restrict__ Wf, short* __restrict__ WG) {
    int id = blockIdx.x * blockDim.x + threadIdx.x;
    if (id < 4 * 8 * 512) {
        int i = id & 7;
        int l = (id >> 3) & 63;
        int rest = id >> 9;
        int q = rest % 8;
        int s = rest / 8;
        int k = s * 32 + (l >> 4) * 8 + i;
        int col = q * 16 + (l & 15);
        WG[id] = (short)f2bf(Wf[(size_t)k * 128 + col]);
    }
}

// ---------------------------------------------------------------------------
// CSR construction (deterministic, dual-ized)
// ---------------------------------------------------------------------------
__global__ void k_counts(const int* __restrict__ dst_a, const int* __restrict__ dst_b,
                         int* __restrict__ cnt_c, int* __restrict__ cnt_i, int n_e) {
    int i = blockIdx.x * blockDim.x + threadIdx.x;
    if (i < n_e) {
        atomicAdd(&cnt_c[dst_a[i]], 1);
        atomicAdd(&cnt_i[dst_b[i]], 1);
    }
}

__device__ inline void scan1_body(const int* cnt, int* off, int* bsum, int n, int blk) {
    __shared__ int wsh[4];
    int tid = threadIdx.x, lane = tid & 63, wid = tid >> 6;
    int base = blk * 2048 + tid * 8;
    int v[8], pref[8];
    int s = 0;
#pragma unroll
    for (int j = 0; j < 8; ++j) {
        v[j] = (base + j < n) ? cnt[base + j] : 0;
        pref[j] = s; s += v[j];
    }
    int x = s;
#pragma unroll
    for (int o = 1; o < 64; o <<= 1) {
        int y = __shfl_up(x, o, 64);
        if (lane >= o) x += y;
    }
    if (lane == 63) wsh[wid] = x;
    __syncthreads();
    int wbase = 0, tot = 0;
#pragma unroll
    for (int w = 0; w < 4; ++w) { if (w < wid) wbase += wsh[w]; tot += wsh[w]; }
    int tbase = wbase + (x - s);
#pragma unroll
    for (int j = 0; j < 8; ++j)
        if (base + j < n) off[base + j] = tbase + pref[j];
    if (tid == 0) bsum[blk] = tot;
}

__global__ void k_scan1_dual(const int* __restrict__ cnt_c, int* __restrict__ off_c,
                             int* __restrict__ bsum_c, int n_c, int nb_c,
                             const int* __restrict__ cnt_i, int* __restrict__ off_i,
                             int* __restrict__ bsum_i, int n_i) {
    if ((int)blockIdx.x < nb_c) scan1_body(cnt_c, off_c, bsum_c, n_c, blockIdx.x);
    else scan1_body(cnt_i, off_i, bsum_i, n_i, blockIdx.x - nb_c);
}

__global__ void k_scan2_dual(int* __restrict__ bsum_c, int nb_c,
                             int* __restrict__ bsum_i, int nb_i) {
    __shared__ int wsh[4];
    int* bsum = blockIdx.x ? bsum_i : bsum_c;
    int nb = blockIdx.x ? nb_i : nb_c;
    int tid = threadIdx.x, lane = tid & 63, wid = tid >> 6;
    int v = (tid < nb) ? bsum[tid] : 0;
    int x = v;
#pragma unroll
    for (int o = 1; o < 64; o <<= 1) {
        int y = __shfl_up(x, o, 64);
        if (lane >= o) x += y;
    }
    if (lane == 63) wsh[wid] = x;
    __syncthreads();
    int wbase = 0;
#pragma unroll
    for (int w = 0; w < 4; ++w) if (w < wid) wbase += wsh[w];
    if (tid < nb) bsum[tid] = wbase + (x - v);
}

__global__ void k_scan3_dual(int* __restrict__ off_c, const int* __restrict__ bsum_c,
                             int n_c,
                             int* __restrict__ off_i, const int* __restrict__ bsum_i,
                             int n_i) {
    int i = blockIdx.x * blockDim.x + threadIdx.x;
    if (i < n_c) off_c[i] += bsum_c[i >> 11];
    else if (i < n_c + n_i) {
        int j = i - n_c;
        off_i[j] += bsum_i[j >> 11];
    }
}

__global__ void k_scatter_dual(
    const int* __restrict__ dst0, const int* __restrict__ src0,
    const int* __restrict__ off0, int* __restrict__ cur0, int* __restrict__ el0,
    const int* __restrict__ dst1, const int* __restrict__ src1,
    const int* __restrict__ off1, int* __restrict__ cur1, int* __restrict__ el1,
    int n_e, int nb_e) {
    bool sec = (int)blockIdx.x >= nb_e;
    const int* dst = sec ? dst1 : dst0;
    const int* src = sec ? src1 : src0;
    const int* off = sec ? off1 : off0;
    int* cursor = sec ? cur1 : cur0;
    int* elist = sec ? el1 : el0;
    int i = (sec ? blockIdx.x - nb_e : blockIdx.x) * blockDim.x + threadIdx.x;
    if (i < n_e) {
        int d = dst[i];
        int pos = off[d] + atomicAdd(&cursor[d], 1);
        elist[pos] = src[i];
    }
}

// ---------------------------------------------------------------------------
// MFMA GEMM v9 (proven): bf16 A, RTN bf16 W, double-buffered phases.
// ---------------------------------------------------------------------------
template <int KSTEPS, int NCT, int EPI, int OUTBF>
__global__ __launch_bounds__(256, 4) void k_mgemm9_dual(
    const unsigned short* __restrict__ S0, const unsigned short* __restrict__ S1,
    int sstride,
    const short* __restrict__ WG0, const short* __restrict__ WG1,
    const float* __restrict__ bias,
    void* __restrict__ O0, void* __restrict__ O1, int ostride,
    int nblk0, int n0, int n1)
{
    constexpr int NQW = NCT / 2;
    constexpr int PHU = NCT * 64;
    __shared__ short lw[2][PHU * 8];
    int b = blockIdx.x;
    bool sec = b >= nblk0;
    const unsigned short* S = sec ? S1 : S0;
    const short* WG = sec ? WG1 : WG0;
    void* OUT = sec ? O1 : O0;
    int n = sec ? n1 : n0;
    int r0 = (sec ? b - nblk0 : b) * 64;

    int tid = threadIdx.x;
    int l = tid & 63, w = tid >> 6;
    int rt = w >> 1, cg = w & 1;
    int g = l >> 4, ln = l & 15;
    int rb = r0 + rt * 32;
    int rowc0 = rb + ln;      if (rowc0 >= n) rowc0 = n - 1;
    int rowc1 = rb + 16 + ln; if (rowc1 >= n) rowc1 = n - 1;

#pragma unroll
    for (int t = 0; t < PHU / 256; ++t)
        gl_lds16(WG + ((size_t)(t * 256 + tid)) * 8,
                 &lw[0][(size_t)(t * 256 + w * 64) * 8]);

    bf16x8 u0[KSTEPS], u1[KSTEPS];
#pragma unroll
    for (int s = 0; s < KSTEPS; ++s) {
        u0[s] = *(const bf16x8*)&S[(size_t)rowc0 * sstride + s * 32 + g * 8];
        u1[s] = *(const bf16x8*)&S[(size_t)rowc1 * sstride + s * 32 + g * 8];
    }

    f32x4 acc0[NQW], acc1[NQW];
#pragma unroll
    for (int c = 0; c < NQW; ++c) {
        acc0[c] = (f32x4){0.f, 0.f, 0.f, 0.f};
        acc1[c] = (f32x4){0.f, 0.f, 0.f, 0.f};
    }
    __syncthreads();

#pragma unroll
    for (int s = 0; s < KSTEPS; ++s) {
        if (s + 1 < KSTEPS) {
#pragma unroll
            for (int t = 0; t < PHU / 256; ++t)
                gl_lds16(WG + ((size_t)(s + 1) * PHU + t * 256 + tid) * 8,
                         &lw[(s + 1) & 1][(size_t)(t * 256 + w * 64) * 8]);
        }
        const short* lb = lw[s & 1];
#pragma unroll
        for (int c = 0; c < NQW; ++c) {
            int q = cg * NQW + c;
            bf16x8 wv = *(const bf16x8*)&lb[((size_t)q * 64 + l) * 8];
            acc0[c] = __builtin_amdgcn_mfma_f32_16x16x32_bf16(u0[s], wv, acc0[c], 0, 0, 0);
            acc1[c] = __builtin_amdgcn_mfma_f32_16x16x32_bf16(u1[s], wv, acc1[c], 0, 0, 0);
        }
        __syncthreads();
    }

#pragma unroll
    for (int c = 0; c < NQW; ++c) {
        int col = (cg * NQW + c) * 16 + ln;
        float bv = (EPI == 1) ? bias[col] : 0.f;
#pragma unroll
        for (int i = 0; i < 4; ++i) {
            int gr0 = rb + g * 4 + i;
            int gr1 = gr0 + 16;
            float v0 = acc0[c][i], v1 = acc1[c][i];
            if (EPI == 1) { v0 = fmaxf(v0 + bv, 0.f); v1 = fmaxf(v1 + bv, 0.f); }
            if (OUTBF == 1) {
                unsigned short* O = (unsigned short*)OUT;
                if (gr0 < n) O[(size_t)gr0 * ostride + col] = f2bf(v0);
                if (gr1 < n) O[(size_t)gr1 * ostride + col] = f2bf(v1);
            } else {
                float* O = (float*)OUT;
                if (gr0 < n) O[(size_t)gr0 * ostride + col] = v0;
                if (gr1 < n) O[(size_t)gr1 * ostride + col] = v1;
            }
        }
    }
}

// ---------------------------------------------------------------------------
// GRU v12 FUSED (R17-proven): 256 threads, 24 KB lw (8 phases) + 17.4 KB xs
// -> 3 blocks/CU. Gather unrolled x4 (loads hoisted, accumulation sequential).
// ---------------------------------------------------------------------------
__global__ __launch_bounds__(256, 3) void k_gru12_dual(
    const unsigned short* __restrict__ P0, const unsigned short* __restrict__ Q0,
    const int* __restrict__ el0, const int* __restrict__ of0,
    const int* __restrict__ ct0, const float* __restrict__ mb0,
    unsigned short* __restrict__ H0, const short* __restrict__ WGa,
    const float* __restrict__ cba,
    const unsigned short* __restrict__ P1, const unsigned short* __restrict__ Q1,
    const int* __restrict__ el1, const int* __restrict__ of1,
    const int* __restrict__ ct1, const float* __restrict__ mb1,
    unsigned short* __restrict__ H1, const short* __restrict__ WGb,
    const float* __restrict__ cbb,
    int nblk0, int n0, int n1)
{
    constexpr int PHU1 = 24 * 64;           // units per k-step
    __shared__ short lw[PHU1 * 8];          // 24 KB
    __shared__ unsigned short xs[64][136];  // 17.4 KB
    int b = blockIdx.x;
    bool sec = b >= nblk0;
    const unsigned short* Pother = sec ? P1 : P0;
    const unsigned short* Qown   = sec ? Q1 : Q0;   // pre-offset +128 cols
    const int* elist = sec ? el1 : el0;
    const int* off   = sec ? of1 : of0;
    const int* cnt   = sec ? ct1 : ct0;
    const float* mb  = sec ? mb1 : mb0;
    unsigned short* state = sec ? H1 : H0;
    const short* WG = sec ? WGb : WGa;
    const float* cb = sec ? cbb : cba;
    int n = sec ? n1 : n0;
    int r0 = (sec ? b - nblk0 : b) * 64;

    int tid = threadIdx.x;
    int l = tid & 63, w = tid >> 6;
    int rt = w >> 1, cg = w & 1;
    int g = l >> 4, ln = l & 15;
    int rb = r0 + rt * 32;

    // ---- stage k-step 0 weights NOW (hidden under the gather) ----
#pragma unroll
    for (int t = 0; t < 6; ++t)
        gl_lds16(WG + ((size_t)(t * 256 + tid)) * 8,
                 &lw[(size_t)(t * 256 + w * 64) * 8]);

    // ---- fused aggregation (bf16 gather, unroll x4): x rows into xs ----
    {
        int lr = tid >> 2;
        int cq = (tid & 3) * 32;
        int node = r0 + lr; if (node >= n) node = n - 1;
        int deg = cnt[node];
        float av[32];
#pragma unroll
        for (int k = 0; k < 32; ++k) av[k] = 0.f;
        if (deg > 0) {
            int o = off[node];
            float qvf[32];
#pragma unroll
            for (int jj = 0; jj < 4; ++jj) {
                u16x8 qv8 = *(const u16x8*)&Qown[(size_t)node * 256 + cq + jj * 8];
#pragma unroll
                for (int k = 0; k < 8; ++k)
                    qvf[jj * 8 + k] = bf2f(qv8[k]) + mb[cq + jj * 8 + k];
            }
            int e = 0;
            for (; e + 4 <= deg; e += 4) {
                int s0 = elist[o + e],     s1 = elist[o + e + 1];
                int s2 = elist[o + e + 2], s3 = elist[o + e + 3];
                const unsigned short* pr0 = Pother + (size_t)s0 * 256 + cq;
                const unsigned short* pr1 = Pother + (size_t)s1 * 256 + cq;
                const unsigned short* pr2 = Pother + (size_t)s2 * 256 + cq;
                const unsigned short* pr3 = Pother + (size_t)s3 * 256 + cq;
                u16x8 p0[4], p1[4], p2[4], p3[4];
#pragma unroll
                for (int jj = 0; jj < 4; ++jj) p0[jj] = *(const u16x8*)&pr0[jj * 8];
#pragma unroll
                for (int jj = 0; jj < 4; ++jj) p1[jj] = *(const u16x8*)&pr1[jj * 8];
#pragma unroll
                for (int jj = 0; jj < 4; ++jj) p2[jj] = *(const u16x8*)&pr2[jj * 8];
#pragma unroll
                for (int jj = 0; jj < 4; ++jj) p3[jj] = *(const u16x8*)&pr3[jj * 8];
#pragma unroll
                for (int jj = 0; jj < 4; ++jj)
#pragma unroll
                    for (int k = 0; k < 8; ++k)
                        av[jj * 8 + k] += fmaxf(bf2f(p0[jj][k]) + qvf[jj * 8 + k], 0.f);
#pragma unroll
                for (int jj = 0; jj < 4; ++jj)
#pragma unroll
                    for (int k = 0; k < 8; ++k)
                        av[jj * 8 + k] += fmaxf(bf2f(p1[jj][k]) + qvf[jj * 8 + k], 0.f);
#pragma unroll
                for (int jj = 0; jj < 4; ++jj)
#pragma unroll
                    for (int k = 0; k < 8; ++k)
                        av[jj * 8 + k] += fmaxf(bf2f(p2[jj][k]) + qvf[jj * 8 + k], 0.f);
#pragma unroll
                for (int jj = 0; jj < 4; ++jj)
#pragma unroll
                    for (int k = 0; k < 8; ++k)
                        av[jj * 8 + k] += fmaxf(bf2f(p3[jj][k]) + qvf[jj * 8 + k], 0.f);
            }
            for (; e < deg; ++e) {
                int s0 = elist[o + e];
                const unsigned short* pr0 = Pother + (size_t)s0 * 256 + cq;
#pragma unroll
                for (int jj = 0; jj < 4; ++jj) {
                    u16x8 pv = *(const u16x8*)&pr0[jj * 8];
#pragma unroll
                    for (int k = 0; k < 8; ++k)
                        av[jj * 8 + k] += fmaxf(bf2f(pv[k]) + qvf[jj * 8 + k], 0.f);
                }
            }
            float inv = 1.0f / (float)deg;
#pragma unroll
            for (int k = 0; k < 32; ++k) av[k] *= inv;
        }
#pragma unroll
        for (int jj = 0; jj < 4; ++jj) {
            u16x8 o8;
#pragma unroll
            for (int k = 0; k < 8; ++k) o8[k] = f2bf(av[jj * 8 + k]);
            *(u16x8*)&xs[lr][cq + jj * 8] = o8;
        }
    }
    __syncthreads();   // gather + stage(0) both complete & visible

    // ---- x fragments direct from bf16 xs ----
    int lrow0 = rt * 32 + ln;
    int lrow1 = lrow0 + 16;
    bf16x8 u0[4], u1[4];
#pragma unroll
    for (int ss = 0; ss < 4; ++ss) {
        u0[ss] = *(const bf16x8*)&xs[lrow0][ss * 32 + g * 8];
        u1[ss] = *(const bf16x8*)&xs[lrow1][ss * 32 + g * 8];
    }

    f32x4 acc0[16], acc1[16];
#pragma unroll
    for (int c = 0; c < 16; ++c) {
        acc0[c] = (f32x4){0.f, 0.f, 0.f, 0.f};
        acc1[c] = (f32x4){0.f, 0.f, 0.f, 0.f};
    }

#pragma unroll
    for (int s = 0; s < 8; ++s) {
        const int ss = s & 3;
        if (s > 0) {
#pragma unroll
            for (int t = 0; t < 6; ++t)
                gl_lds16(WG + ((size_t)s * PHU1 + t * 256 + tid) * 8,
                         &lw[(size_t)(t * 256 + w * 64) * 8]);
            if (s == 4) {
#pragma unroll
                for (int i = 0; i < 4; ++i) {
                    int id = i * 256 + tid;
                    int r = id >> 4, c8 = id & 15;
                    int gr = r0 + r; if (gr >= n) gr = n - 1;
                    *(u16x8*)&xs[r][c8 * 8] =
                        *(const u16x8*)&state[(size_t)gr * 128 + c8 * 8];
                }
            }
            __syncthreads();   // weights (and h tile at s==4) visible
            if (s == 4) {
#pragma unroll
                for (int s2 = 0; s2 < 4; ++s2) {
                    u0[s2] = *(const bf16x8*)&xs[lrow0][s2 * 32 + g * 8];
                    u1[s2] = *(const bf16x8*)&xs[lrow1][s2 * 32 + g * 8];
                }
            }
        }
#pragma unroll
        for (int jp = 0; jp < 4; ++jp) {
            int qz = cg * 4 + jp;
            int qr = 8 + cg * 4 + jp;
            int qh = 16 + cg * 4 + jp;
            int aih = (s < 4) ? (8 + jp) : (12 + jp);
#define PROC(Q, AI) do {                                                        \
            bf16x8 wv = *(const bf16x8*)&lw[(((size_t)(Q)) * 64 + l) * 8];      \
            acc0[AI] = __builtin_amdgcn_mfma_f32_16x16x32_bf16(u0[ss], wv, acc0[AI], 0, 0, 0); \
            acc1[AI] = __builtin_amdgcn_mfma_f32_16x16x32_bf16(u1[ss], wv, acc1[AI], 0, 0, 0); \
        } while (0)
            PROC(qz, jp);
            PROC(qr, 4 + jp);
            PROC(qh, aih);
#undef PROC
        }
        if (s + 1 < 8) __syncthreads();  // all waves done reading lw before restage
    }

    // ---- in-register GRU epilogue; h from bf16 xs; bf16 state write ----
#pragma unroll
    for (int jp = 0; jp < 4; ++jp) {
        int d = (cg * 4 + jp) * 16 + ln;
        float bz = cb[d], brr = cb[128 + d], bxh = cb[256 + d], bhh = cb[384 + d];
#pragma unroll
        for (int rs = 0; rs < 2; ++rs) {
            f32x4 az = rs ? acc1[jp] : acc0[jp];
            f32x4 ar = rs ? acc1[4 + jp] : acc0[4 + jp];
            f32x4 axh = rs ? acc1[8 + jp] : acc0[8 + jp];
            f32x4 ahh = rs ? acc1[12 + jp] : acc0[12 + jp];
#pragma unroll
            for (int i = 0; i < 4; ++i) {
                int lr = rt * 32 + rs * 16 + g * 4 + i;
                int gr = r0 + lr;
                if (gr < n) {
                    float h = bf2f(xs[lr][d]);
                    float z = fast_sigmoid(az[i] + bz);
                    float r = fast_sigmoid(ar[i] + brr);
                    float hc = fast_tanh(axh[i] + bxh + r * (ahh[i] + bhh));
                    state[(size_t)gr * 128 + d] = f2bf(z * h + (1.0f - z) * hc);
                }
            }
        }
    }
}

// ---------------------------------------------------------------------------
// readout stages 2+3 (h1 bf16)
// ---------------------------------------------------------------------------
__global__ __launch_bounds__(256) void k_read2(
    const unsigned short* __restrict__ h1,
    const float* __restrict__ W2, const float* __restrict__ b2,
    const float* __restrict__ W3, const float* __restrict__ b3,
    float* __restrict__ out, int n)
{
    __shared__ float W2ls[128][64];
    __shared__ float W3ls[64][16];
    __shared__ float h1ls[8][132];
    __shared__ float h2ls[8][66];
    __shared__ float lgls[8][16];
    int tid = threadIdx.x;
    int r0 = blockIdx.x * 8;

#pragma unroll
    for (int i = 0; i < 8; ++i) {
        int id = i * 256 + tid;
        int kr = id >> 4, c4 = id & 15;
        *(float4*)&W2ls[kr][c4 * 4] = *(const float4*)&W2[kr * 64 + c4 * 4];
    }
    for (int id = tid; id < 960; id += 256) {
        W3ls[id / 15][id % 15] = W3[id];
    }
    {
        int r = tid >> 5, c4 = tid & 31;
        int gr = r0 + r; if (gr >= n) gr = n - 1;
        u16x4 v = *(const u16x4*)&h1[(size_t)gr * 128 + c4 * 4];
#pragma unroll
        for (int k = 0; k < 4; ++k) h1ls[r][c4 * 4 + k] = bf2f(v[k]);
    }
    __syncthreads();

    {
        int row = tid >> 5, c = tid & 31;
        float a0 = b2[c], a1 = b2[c + 32];
        for (int k = 0; k < 128; ++k) {
            float h = h1ls[row][k];
            a0 = fmaf(h, W2ls[k][c], a0);
            a1 = fmaf(h, W2ls[k][c + 32], a1);
        }
        h2ls[row][c] = fmaxf(a0, 0.f);
        h2ls[row][c + 32] = fmaxf(a1, 0.f);
    }
    __syncthreads();

    if (tid < 120) {
        int row = tid / 15, c = tid % 15;
        float a = b3[c];
        for (int k = 0; k < 64; ++k) a = fmaf(h2ls[row][k], W3ls[k][c], a);
        lgls[row][c] = a;
    }
    __syncthreads();

    if (tid < 120) {
        int row = tid / 15, c = tid % 15;
        int gr = r0 + row;
        if (gr < n) {
            float m = -1e30f;
#pragma unroll
            for (int k = 0; k < 15; ++k) m = fmaxf(m, lgls[row][k]);
            float s = 0.f;
#pragma unroll
            for (int k = 0; k < 15; ++k) s += expf(lgls[row][k] - m);
            out[(size_t)gr * 15 + c] = expf(lgls[row][c] - m) / s;
        }
    }
}

// ---------------------------------------------------------------------------
extern "C" void kernel_launch(void* const* d_in, const int* in_sizes, int n_in,
                              void* d_out, int out_size, void* d_ws, size_t ws_size,
                              hipStream_t stream) {
    const float* feat   = (const float*)d_in[0];
    const int*   src_ip = (const int*)d_in[1];
    const int*   dst_ip = (const int*)d_in[2];
    const int*   src_cn = (const int*)d_in[3];
    const int*   dst_cn = (const int*)d_in[4];
    const float* Wm1 = (const float*)d_in[7];
    const float* bm1 = (const float*)d_in[8];
    const float* Wm2 = (const float*)d_in[9];
    const float* bm2 = (const float*)d_in[10];
    const float* k_ip  = (const float*)d_in[11];
    const float* rk_ip = (const float*)d_in[12];
    const float* bi_ip = (const float*)d_in[13];
    const float* br_ip = (const float*)d_in[14];
    const float* k_cn  = (const float*)d_in[15];
    const float* rk_cn = (const float*)d_in[16];
    const float* bi_cn = (const float*)d_in[17];
    const float* br_cn = (const float*)d_in[18];
    const float* Wr1 = (const float*)d_in[19];
    const float* br1 = (const float*)d_in[20];
    const float* Wr2 = (const float*)d_in[21];
    const float* br2 = (const float*)d_in[22];
    const float* Wr3 = (const float*)d_in[23];
    const float* br3 = (const float*)d_in[24];

    const int n_e = in_sizes[1];
    const int n_c = in_sizes[0] / FEAT;
    const int n_i = 50000;

    auto align = [](size_t x) { return (x + 255) & ~(size_t)255; };
    char* ws = (char*)d_ws;
    size_t off = 0;
    unsigned short* ip_state   = (unsigned short*)(ws + off); off = align(off + (size_t)n_i * D * 2);
    unsigned short* conn_state = (unsigned short*)(ws + off); off = align(off + (size_t)n_c * D * 2);
    unsigned short* PQ_ip = (unsigned short*)(ws + off); off = align(off + (size_t)n_i * 256 * 2);
    unsigned short* PQ_cn = (unsigned short*)(ws + off); off = align(off + (size_t)n_c * 256 * 2);
    unsigned short* h1buf = (unsigned short*)(ws + off); off = align(off + (size_t)n_c * 128 * 2);
    short* WGpq_ip    = (short*)(ws + off); off = align(off + (size_t)4 * 16 * 512 * 2);
    short* WGpq_cn    = (short*)(ws + off); off = align(off + (size_t)4 * 16 * 512 * 2);
    short* WGg_ip     = (short*)(ws + off); off = align(off + (size_t)8 * 24 * 512 * 2);
    short* WGg_cn     = (short*)(ws + off); off = align(off + (size_t)8 * 24 * 512 * 2);
    short* WGr1       = (short*)(ws + off); off = align(off + (size_t)4 * 8 * 512 * 2);
    float* cb_ip      = (float*)(ws + off); off = align(off + (size_t)512 * 4);
    float* cb_cn      = (float*)(ws + off); off = align(off + (size_t)512 * 4);
    int*   zb         = (int*)(ws + off);   off = align(off + (size_t)(2 * n_c + 2 * n_i) * 4);
    int*   cnt_c      = zb;
    int*   cnt_i      = zb + n_c;
    int*   cursor_c   = zb + n_c + n_i;
    int*   cursor_i   = zb + 2 * n_c + n_i;
    int*   off_c      = (int*)(ws + off);   off = align(off + (size_t)n_c * 4);
    int*   off_i      = (int*)(ws + off);   off = align(off + (size_t)n_i * 4);
    int*   elist_c    = (int*)(ws + off);   off = align(off + (size_t)n_e * 4);
    int*   elist_i    = (int*)(ws + off);   off = align(off + (size_t)n_e * 4);
    int*   bsum_c     = (int*)(ws + off);   off = align(off + (size_t)64 * 4);
    int*   bsum_i     = (int*)(ws + off);   off = align(off + (size_t)64 * 4);

    // ---- init states (bf16, fused) ----
    int init_total = n_i * D + n_c * D;
    k_init_dual<<<(init_total + 255) / 256, 256, 0, stream>>>(
        ip_state, conn_state, feat, n_i * D, init_total);

    // ---- weight prep (RTN bf16, direct packs) ----
    k_pack_pq_dual<<<(4 * 16 * 512 + 255) / 256, 256, 0, stream>>>(
        Wm1, Wm2, WGpq_ip, WGpq_cn);
    {
        int nbg = (8 * 24 * 512 + 255) / 256;
        k_pack_gru_dual<<<2 * nbg, 256, 0, stream>>>(
            k_ip, rk_ip, WGg_ip, k_cn, rk_cn, WGg_cn, nbg);
    }
    k_pack_r1<<<(4 * 8 * 512 + 255) / 256, 256, 0, stream>>>(Wr1, WGr1);
    k_gbias_dual<<<2, 128, 0, stream>>>(bi_ip, br_ip, cb_ip, bi_cn, br_cn, cb_cn);

    // ---- CSR build (dual-ized) ----
    hipMemsetAsync(zb, 0, (size_t)(2 * n_c + 2 * n_i) * 4, stream);
    k_counts<<<(n_e + 255) / 256, 256, 0, stream>>>(dst_ip, dst_cn, cnt_c, cnt_i, n_e);
    int nb_c = (n_c + 2047) / 2048, nb_i = (n_i + 2047) / 2048;
    k_scan1_dual<<<nb_c + nb_i, 256, 0, stream>>>(
        cnt_c, off_c, bsum_c, n_c, nb_c, cnt_i, off_i, bsum_i, n_i);
    k_scan2_dual<<<2, 256, 0, stream>>>(bsum_c, nb_c, bsum_i, nb_i);
    k_scan3_dual<<<(n_c + n_i + 255) / 256, 256, 0, stream>>>(
        off_c, bsum_c, n_c, off_i, bsum_i, n_i);
    {
        int nb_e = (n_e + 255) / 256;
        k_scatter_dual<<<2 * nb_e, 256, 0, stream>>>(
            dst_ip, src_ip, off_c, cursor_c, elist_c,
            dst_cn, src_cn, off_i, cursor_i, elist_i, n_e, nb_e);
    }

    int b64_i = (n_i + 63) / 64;
    int b64_c = (n_c + 63) / 64;

    for (int t = 0; t < T_STEPS; ++t) {
        k_mgemm9_dual<4, 16, 0, 1><<<b64_i + b64_c, 256, 0, stream>>>(
            ip_state, conn_state, 128, WGpq_ip, WGpq_cn, nullptr,
            PQ_ip, PQ_cn, 256, b64_i, n_i, n_c);
        // fused agg+GRU: ip gathers P2 (PQ_cn), conn gathers P1 (PQ_ip)
        k_gru12_dual<<<b64_i + b64_c, 256, 0, stream>>>(
            PQ_cn, PQ_ip + 128, elist_i, off_i, cnt_i, bm2, ip_state, WGg_ip, cb_ip,
            PQ_ip, PQ_cn + 128, elist_c, off_c, cnt_c, bm1, conn_state, WGg_cn, cb_cn,
            b64_i, n_i, n_c);
    }

    // readout (bf16 A, bf16 h1)
    k_mgemm9_dual<4, 8, 1, 1><<<b64_c, 256, 0, stream>>>(
        conn_state, conn_state, 128, WGr1, WGr1, br1,
        h1buf, h1buf, 128, b64_c, n_c, n_c);
    k_read2<<<(n_c + 7) / 8, 256, 0, stream>>>(
        h1buf, Wr2, br2, Wr3, br3, (float*)d_out, n_c);
}

// Round 20
// 1257.784 us; speedup vs baseline: 1.4186x; 1.4186x over previous
//
#include <hip/hip_runtime.h>
#include <math.h>

#define D 128
#define T_STEPS 8
#define FEAT 26

typedef short bf16x8 __attribute__((ext_vector_type(8)));
typedef unsigned short u16x8 __attribute__((ext_vector_type(8)));
typedef unsigned short u16x4 __attribute__((ext_vector_type(4)));
typedef float f32x4 __attribute__((ext_vector_type(4)));

__device__ inline unsigned short f2bf(float f) {
    unsigned b = __float_as_uint(f);
    b += 0x7FFFu + ((b >> 16) & 1u);
    return (unsigned short)(b >> 16);
}
__device__ inline float bf2f(unsigned short u) {
    return __uint_as_float(((unsigned)u) << 16);
}

// async global->LDS, 16B per lane; lds dest must be wave-uniform base
__device__ inline void gl_lds16(const void* g, void* l) {
    __builtin_amdgcn_global_load_lds(
        (const __attribute__((address_space(1))) void*)g,
        (__attribute__((address_space(3))) void*)l, 16, 0, 0);
}

// fast sigmoid/tanh via v_exp_f32 (exp2) + v_rcp_f32
__device__ inline float fast_sigmoid(float x) {
    float e = __builtin_amdgcn_exp2f(-1.442695041f * x);
    return __builtin_amdgcn_rcpf(1.0f + e);
}
__device__ inline float fast_tanh(float x) {
    float e = __builtin_amdgcn_exp2f(2.885390082f * x);
    return 1.0f - 2.0f * __builtin_amdgcn_rcpf(1.0f + e);
}

// ---------------------------------------------------------------------------
// fused init (bf16 state)
// ---------------------------------------------------------------------------
__global__ void k_init_dual(unsigned short* __restrict__ ip_state,
                            unsigned short* __restrict__ conn_state,
                            const float* __restrict__ feat, int ni_elems,
                            int total) {
    int i = blockIdx.x * blockDim.x + threadIdx.x;
    if (i < ni_elems) {
        ip_state[i] = 0x3F80;
    } else if (i < total) {
        int j = i - ni_elems;
        int r = j >> 7, d = j & 127;
        conn_state[j] = (d < FEAT) ? f2bf(feat[r * FEAT + d]) : (unsigned short)0;
    }
}

__global__ void k_gbias_dual(const float* __restrict__ bi0, const float* __restrict__ br0,
                             float* __restrict__ cb0,
                             const float* __restrict__ bi1, const float* __restrict__ br1,
                             float* __restrict__ cb1) {
    const float* bi = blockIdx.x ? bi1 : bi0;
    const float* br = blockIdx.x ? br1 : br0;
    float* cb = blockIdx.x ? cb1 : cb0;
    int d = threadIdx.x;
    cb[d] = bi[d] + br[d];
    cb[128 + d] = bi[128 + d] + br[128 + d];
    cb[256 + d] = bi[256 + d];
    cb[384 + d] = br[256 + d];
}

// ---------------------------------------------------------------------------
// weight packs (RTN bf16, direct)
// ---------------------------------------------------------------------------
__global__ void k_pack_pq_dual(const float* __restrict__ Wm1,
                               const float* __restrict__ Wm2,
                               short* __restrict__ WGip, short* __restrict__ WGcn) {
    int id = blockIdx.x * blockDim.x + threadIdx.x;
    if (id < 4 * 16 * 512) {
        int i = id & 7;
        int l = (id >> 3) & 63;
        int rest = id >> 9;
        int q = rest % 16;
        int s = rest / 16;
        int k = s * 32 + (l >> 4) * 8 + i;
        int col = q * 16 + (l & 15);
        float fip = (col < 128) ? Wm1[k * 128 + col] : Wm2[(128 + k) * 128 + (col - 128)];
        float fcn = (col < 128) ? Wm2[k * 128 + col] : Wm1[(128 + k) * 128 + (col - 128)];
        WGip[id] = (short)f2bf(fip);
        WGcn[id] = (short)f2bf(fcn);
    }
}

__global__ void k_pack_gru_dual(const float* __restrict__ K0, const float* __restrict__ RK0,
                                short* __restrict__ WG0,
                                const float* __restrict__ K1, const float* __restrict__ RK1,
                                short* __restrict__ WG1, int nblk0) {
    int total = 8 * 24 * 512;
    bool sec = blockIdx.x >= nblk0;
    const float* K = sec ? K1 : K0;
    const float* RK = sec ? RK1 : RK0;
    short* WG = sec ? WG1 : WG0;
    int id = (sec ? blockIdx.x - nblk0 : blockIdx.x) * blockDim.x + threadIdx.x;
    if (id < total) {
        int i = id & 7;
        int l = (id >> 3) & 63;
        int rest = id >> 9;
        int q = rest % 24;
        int s = rest / 24;
        int ct = (s < 4) ? q : (q < 16 ? q : q + 8);
        int k = s * 32 + (l >> 4) * 8 + i;
        int col = ct * 16 + (l & 15);
        float v = 0.f;
        if (k < 128) {
            if (col < 384) v = K[k * 384 + col];
        } else {
            int kk = k - 128;
            if (col < 256) v = RK[kk * 384 + col];
            else if (col >= 384) v = RK[kk * 384 + (col - 128)];
        }
        WG[id] = (short)f2bf(v);
    }
}

__global__ void k_pack_r1(const float* __restrict__ Wf, short* __restrict__ WG) {
    int id = blockIdx.x * blockDim.x + threadIdx.x;
    if (id < 4 * 8 * 512) {
        int i = id & 7;
        int l = (id >> 3) & 63;
        int rest = id >> 9;
        int q = rest % 8;
        int s = rest / 8;
        int k = s * 32 + (l >> 4) * 8 + i;
        int col = q * 16 + (l & 15);
        WG[id] = (short)f2bf(Wf[(size_t)k * 128 + col]);
    }
}

// ---------------------------------------------------------------------------
// CSR construction (deterministic, dual-ized)
// ---------------------------------------------------------------------------
__global__ void k_counts(const int* __restrict__ dst_a, const int* __restrict__ dst_b,
                         int* __restrict__ cnt_c, int* __restrict__ cnt_i, int n_e) {
    int i = blockIdx.x * blockDim.x + threadIdx.x;
    if (i < n_e) {
        atomicAdd(&cnt_c[dst_a[i]], 1);
        atomicAdd(&cnt_i[dst_b[i]], 1);
    }
}

__device__ inline void scan1_body(const int* cnt, int* off, int* bsum, int n, int blk) {
    __shared__ int wsh[4];
    int tid = threadIdx.x, lane = tid & 63, wid = tid >> 6;
    int base = blk * 2048 + tid * 8;
    int v[8], pref[8];
    int s = 0;
#pragma unroll
    for (int j = 0; j < 8; ++j) {
        v[j] = (base + j < n) ? cnt[base + j] : 0;
        pref[j] = s; s += v[j];
    }
    int x = s;
#pragma unroll
    for (int o = 1; o < 64; o <<= 1) {
        int y = __shfl_up(x, o, 64);
        if (lane >= o) x += y;
    }
    if (lane == 63) wsh[wid] = x;
    __syncthreads();
    int wbase = 0, tot = 0;
#pragma unroll
    for (int w = 0; w < 4; ++w) { if (w < wid) wbase += wsh[w]; tot += wsh[w]; }
    int tbase = wbase + (x - s);
#pragma unroll
    for (int j = 0; j < 8; ++j)
        if (base + j < n) off[base + j] = tbase + pref[j];
    if (tid == 0) bsum[blk] = tot;
}

__global__ void k_scan1_dual(const int* __restrict__ cnt_c, int* __restrict__ off_c,
                             int* __restrict__ bsum_c, int n_c, int nb_c,
                             const int* __restrict__ cnt_i, int* __restrict__ off_i,
                             int* __restrict__ bsum_i, int n_i) {
    if ((int)blockIdx.x < nb_c) scan1_body(cnt_c, off_c, bsum_c, n_c, blockIdx.x);
    else scan1_body(cnt_i, off_i, bsum_i, n_i, blockIdx.x - nb_c);
}

__global__ void k_scan2_dual(int* __restrict__ bsum_c, int nb_c,
                             int* __restrict__ bsum_i, int nb_i) {
    __shared__ int wsh[4];
    int* bsum = blockIdx.x ? bsum_i : bsum_c;
    int nb = blockIdx.x ? nb_i : nb_c;
    int tid = threadIdx.x, lane = tid & 63, wid = tid >> 6;
    int v = (tid < nb) ? bsum[tid] : 0;
    int x = v;
#pragma unroll
    for (int o = 1; o < 64; o <<= 1) {
        int y = __shfl_up(x, o, 64);
        if (lane >= o) x += y;
    }
    if (lane == 63) wsh[wid] = x;
    __syncthreads();
    int wbase = 0;
#pragma unroll
    for (int w = 0; w < 4; ++w) if (w < wid) wbase += wsh[w];
    if (tid < nb) bsum[tid] = wbase + (x - v);
}

__global__ void k_scan3_dual(int* __restrict__ off_c, const int* __restrict__ bsum_c,
                             int n_c,
                             int* __restrict__ off_i, const int* __restrict__ bsum_i,
                             int n_i) {
    int i = blockIdx.x * blockDim.x + threadIdx.x;
    if (i < n_c) off_c[i] += bsum_c[i >> 11];
    else if (i < n_c + n_i) {
        int j = i - n_c;
        off_i[j] += bsum_i[j >> 11];
    }
}

__global__ void k_scatter_dual(
    const int* __restrict__ dst0, const int* __restrict__ src0,
    const int* __restrict__ off0, int* __restrict__ cur0, int* __restrict__ el0,
    const int* __restrict__ dst1, const int* __restrict__ src1,
    const int* __restrict__ off1, int* __restrict__ cur1, int* __restrict__ el1,
    int n_e, int nb_e) {
    bool sec = (int)blockIdx.x >= nb_e;
    const int* dst = sec ? dst1 : dst0;
    const int* src = sec ? src1 : src0;
    const int* off = sec ? off1 : off0;
    int* cursor = sec ? cur1 : cur0;
    int* elist = sec ? el1 : el0;
    int i = (sec ? blockIdx.x - nb_e : blockIdx.x) * blockDim.x + threadIdx.x;
    if (i < n_e) {
        int d = dst[i];
        int pos = off[d] + atomicAdd(&cursor[d], 1);
        elist[pos] = src[i];
    }
}

// ---------------------------------------------------------------------------
// MFMA GEMM v9 (proven): bf16 A, RTN bf16 W, double-buffered phases.
// ---------------------------------------------------------------------------
template <int KSTEPS, int NCT, int EPI, int OUTBF>
__global__ __launch_bounds__(256, 4) void k_mgemm9_dual(
    const unsigned short* __restrict__ S0, const unsigned short* __restrict__ S1,
    int sstride,
    const short* __restrict__ WG0, const short* __restrict__ WG1,
    const float* __restrict__ bias,
    void* __restrict__ O0, void* __restrict__ O1, int ostride,
    int nblk0, int n0, int n1)
{
    constexpr int NQW = NCT / 2;
    constexpr int PHU = NCT * 64;
    __shared__ short lw[2][PHU * 8];
    int b = blockIdx.x;
    bool sec = b >= nblk0;
    const unsigned short* S = sec ? S1 : S0;
    const short* WG = sec ? WG1 : WG0;
    void* OUT = sec ? O1 : O0;
    int n = sec ? n1 : n0;
    int r0 = (sec ? b - nblk0 : b) * 64;

    int tid = threadIdx.x;
    int l = tid & 63, w = tid >> 6;
    int rt = w >> 1, cg = w & 1;
    int g = l >> 4, ln = l & 15;
    int rb = r0 + rt * 32;
    int rowc0 = rb + ln;      if (rowc0 >= n) rowc0 = n - 1;
    int rowc1 = rb + 16 + ln; if (rowc1 >= n) rowc1 = n - 1;

#pragma unroll
    for (int t = 0; t < PHU / 256; ++t)
        gl_lds16(WG + ((size_t)(t * 256 + tid)) * 8,
                 &lw[0][(size_t)(t * 256 + w * 64) * 8]);

    bf16x8 u0[KSTEPS], u1[KSTEPS];
#pragma unroll
    for (int s = 0; s < KSTEPS; ++s) {
        u0[s] = *(const bf16x8*)&S[(size_t)rowc0 * sstride + s * 32 + g * 8];
        u1[s] = *(const bf16x8*)&S[(size_t)rowc1 * sstride + s * 32 + g * 8];
    }

    f32x4 acc0[NQW], acc1[NQW];
#pragma unroll
    for (int c = 0; c < NQW; ++c) {
        acc0[c] = (f32x4){0.f, 0.f, 0.f, 0.f};
        acc1[c] = (f32x4){0.f, 0.f, 0.f, 0.f};
    }
    __syncthreads();

#pragma unroll
    for (int s = 0; s < KSTEPS; ++s) {
        if (s + 1 < KSTEPS) {
#pragma unroll
            for (int t = 0; t < PHU / 256; ++t)
                gl_lds16(WG + ((size_t)(s + 1) * PHU + t * 256 + tid) * 8,
                         &lw[(s + 1) & 1][(size_t)(t * 256 + w * 64) * 8]);
        }
        const short* lb = lw[s & 1];
#pragma unroll
        for (int c = 0; c < NQW; ++c) {
            int q = cg * NQW + c;
            bf16x8 wv = *(const bf16x8*)&lb[((size_t)q * 64 + l) * 8];
            acc0[c] = __builtin_amdgcn_mfma_f32_16x16x32_bf16(u0[s], wv, acc0[c], 0, 0, 0);
            acc1[c] = __builtin_amdgcn_mfma_f32_16x16x32_bf16(u1[s], wv, acc1[c], 0, 0, 0);
        }
        __syncthreads();
    }

#pragma unroll
    for (int c = 0; c < NQW; ++c) {
        int col = (cg * NQW + c) * 16 + ln;
        float bv = (EPI == 1) ? bias[col] : 0.f;
#pragma unroll
        for (int i = 0; i < 4; ++i) {
            int gr0 = rb + g * 4 + i;
            int gr1 = gr0 + 16;
            float v0 = acc0[c][i], v1 = acc1[c][i];
            if (EPI == 1) { v0 = fmaxf(v0 + bv, 0.f); v1 = fmaxf(v1 + bv, 0.f); }
            if (OUTBF == 1) {
                unsigned short* O = (unsigned short*)OUT;
                if (gr0 < n) O[(size_t)gr0 * ostride + col] = f2bf(v0);
                if (gr1 < n) O[(size_t)gr1 * ostride + col] = f2bf(v1);
            } else {
                float* O = (float*)OUT;
                if (gr0 < n) O[(size_t)gr0 * ostride + col] = v0;
                if (gr1 < n) O[(size_t)gr1 * ostride + col] = v1;
            }
        }
    }
}

// ---------------------------------------------------------------------------
// GRU v12 FUSED (R17 exact): 256 threads, 24 KB lw (8 phases) + 17.4 KB xs
// -> 3 blocks/CU. Gather unrolled x2 (proven optimum).
// ---------------------------------------------------------------------------
__global__ __launch_bounds__(256, 3) void k_gru12_dual(
    const unsigned short* __restrict__ P0, const unsigned short* __restrict__ Q0,
    const int* __restrict__ el0, const int* __restrict__ of0,
    const int* __restrict__ ct0, const float* __restrict__ mb0,
    unsigned short* __restrict__ H0, const short* __restrict__ WGa,
    const float* __restrict__ cba,
    const unsigned short* __restrict__ P1, const unsigned short* __restrict__ Q1,
    const int* __restrict__ el1, const int* __restrict__ of1,
    const int* __restrict__ ct1, const float* __restrict__ mb1,
    unsigned short* __restrict__ H1, const short* __restrict__ WGb,
    const float* __restrict__ cbb,
    int nblk0, int n0, int n1)
{
    constexpr int PHU1 = 24 * 64;           // units per k-step
    __shared__ short lw[PHU1 * 8];          // 24 KB
    __shared__ unsigned short xs[64][136];  // 17.4 KB
    int b = blockIdx.x;
    bool sec = b >= nblk0;
    const unsigned short* Pother = sec ? P1 : P0;
    const unsigned short* Qown   = sec ? Q1 : Q0;   // pre-offset +128 cols
    const int* elist = sec ? el1 : el0;
    const int* off   = sec ? of1 : of0;
    const int* cnt   = sec ? ct1 : ct0;
    const float* mb  = sec ? mb1 : mb0;
    unsigned short* state = sec ? H1 : H0;
    const short* WG = sec ? WGb : WGa;
    const float* cb = sec ? cbb : cba;
    int n = sec ? n1 : n0;
    int r0 = (sec ? b - nblk0 : b) * 64;

    int tid = threadIdx.x;
    int l = tid & 63, w = tid >> 6;
    int rt = w >> 1, cg = w & 1;
    int g = l >> 4, ln = l & 15;
    int rb = r0 + rt * 32;

    // ---- stage k-step 0 weights NOW (hidden under the gather) ----
#pragma unroll
    for (int t = 0; t < 6; ++t)
        gl_lds16(WG + ((size_t)(t * 256 + tid)) * 8,
                 &lw[(size_t)(t * 256 + w * 64) * 8]);

    // ---- fused aggregation (bf16 gather, unroll x2): x rows into xs ----
    {
        int lr = tid >> 2;
        int cq = (tid & 3) * 32;
        int node = r0 + lr; if (node >= n) node = n - 1;
        int deg = cnt[node];
        float av[32];
#pragma unroll
        for (int k = 0; k < 32; ++k) av[k] = 0.f;
        if (deg > 0) {
            int o = off[node];
            float qvf[32];
#pragma unroll
            for (int jj = 0; jj < 4; ++jj) {
                u16x8 qv8 = *(const u16x8*)&Qown[(size_t)node * 256 + cq + jj * 8];
#pragma unroll
                for (int k = 0; k < 8; ++k)
                    qvf[jj * 8 + k] = bf2f(qv8[k]) + mb[cq + jj * 8 + k];
            }
            int e = 0;
            for (; e + 2 <= deg; e += 2) {
                int s0 = elist[o + e], s1 = elist[o + e + 1];
                const unsigned short* pr0 = Pother + (size_t)s0 * 256 + cq;
                const unsigned short* pr1 = Pother + (size_t)s1 * 256 + cq;
                u16x8 p0[4], p1[4];
#pragma unroll
                for (int jj = 0; jj < 4; ++jj) p0[jj] = *(const u16x8*)&pr0[jj * 8];
#pragma unroll
                for (int jj = 0; jj < 4; ++jj) p1[jj] = *(const u16x8*)&pr1[jj * 8];
#pragma unroll
                for (int jj = 0; jj < 4; ++jj)
#pragma unroll
                    for (int k = 0; k < 8; ++k)
                        av[jj * 8 + k] += fmaxf(bf2f(p0[jj][k]) + qvf[jj * 8 + k], 0.f);
#pragma unroll
                for (int jj = 0; jj < 4; ++jj)
#pragma unroll
                    for (int k = 0; k < 8; ++k)
                        av[jj * 8 + k] += fmaxf(bf2f(p1[jj][k]) + qvf[jj * 8 + k], 0.f);
            }
            if (e < deg) {
                int s0 = elist[o + e];
                const unsigned short* pr0 = Pother + (size_t)s0 * 256 + cq;
#pragma unroll
                for (int jj = 0; jj < 4; ++jj) {
                    u16x8 pv = *(const u16x8*)&pr0[jj * 8];
#pragma unroll
                    for (int k = 0; k < 8; ++k)
                        av[jj * 8 + k] += fmaxf(bf2f(pv[k]) + qvf[jj * 8 + k], 0.f);
                }
            }
            float inv = 1.0f / (float)deg;
#pragma unroll
            for (int k = 0; k < 32; ++k) av[k] *= inv;
        }
#pragma unroll
        for (int jj = 0; jj < 4; ++jj) {
            u16x8 o8;
#pragma unroll
            for (int k = 0; k < 8; ++k) o8[k] = f2bf(av[jj * 8 + k]);
            *(u16x8*)&xs[lr][cq + jj * 8] = o8;
        }
    }
    __syncthreads();   // gather + stage(0) both complete & visible

    // ---- x fragments direct from bf16 xs ----
    int lrow0 = rt * 32 + ln;
    int lrow1 = lrow0 + 16;
    bf16x8 u0[4], u1[4];
#pragma unroll
    for (int ss = 0; ss < 4; ++ss) {
        u0[ss] = *(const bf16x8*)&xs[lrow0][ss * 32 + g * 8];
        u1[ss] = *(const bf16x8*)&xs[lrow1][ss * 32 + g * 8];
    }

    f32x4 acc0[16], acc1[16];
#pragma unroll
    for (int c = 0; c < 16; ++c) {
        acc0[c] = (f32x4){0.f, 0.f, 0.f, 0.f};
        acc1[c] = (f32x4){0.f, 0.f, 0.f, 0.f};
    }

#pragma unroll
    for (int s = 0; s < 8; ++s) {
        const int ss = s & 3;
        if (s > 0) {
#pragma unroll
            for (int t = 0; t < 6; ++t)
                gl_lds16(WG + ((size_t)s * PHU1 + t * 256 + tid) * 8,
                         &lw[(size_t)(t * 256 + w * 64) * 8]);
            if (s == 4) {
#pragma unroll
                for (int i = 0; i < 4; ++i) {
                    int id = i * 256 + tid;
                    int r = id >> 4, c8 = id & 15;
                    int gr = r0 + r; if (gr >= n) gr = n - 1;
                    *(u16x8*)&xs[r][c8 * 8] =
                        *(const u16x8*)&state[(size_t)gr * 128 + c8 * 8];
                }
            }
            __syncthreads();   // weights (and h tile at s==4) visible
            if (s == 4) {
#pragma unroll
                for (int s2 = 0; s2 < 4; ++s2) {
                    u0[s2] = *(const bf16x8*)&xs[lrow0][s2 * 32 + g * 8];
                    u1[s2] = *(const bf16x8*)&xs[lrow1][s2 * 32 + g * 8];
                }
            }
        }
#pragma unroll
        for (int jp = 0; jp < 4; ++jp) {
            int qz = cg * 4 + jp;
            int qr = 8 + cg * 4 + jp;
            int qh = 16 + cg * 4 + jp;
            int aih = (s < 4) ? (8 + jp) : (12 + jp);
#define PROC(Q, AI) do {                                                        \
            bf16x8 wv = *(const bf16x8*)&lw[(((size_t)(Q)) * 64 + l) * 8];      \
            acc0[AI] = __builtin_amdgcn_mfma_f32_16x16x32_bf16(u0[ss], wv, acc0[AI], 0, 0, 0); \
            acc1[AI] = __builtin_amdgcn_mfma_f32_16x16x32_bf16(u1[ss], wv, acc1[AI], 0, 0, 0); \
        } while (0)
            PROC(qz, jp);
            PROC(qr, 4 + jp);
            PROC(qh, aih);
#undef PROC
        }
        if (s + 1 < 8) __syncthreads();  // all waves done reading lw before restage
    }

    // ---- in-register GRU epilogue; h from bf16 xs; bf16 state write ----
#pragma unroll
    for (int jp = 0; jp < 4; ++jp) {
        int d = (cg * 4 + jp) * 16 + ln;
        float bz = cb[d], brr = cb[128 + d], bxh = cb[256 + d], bhh = cb[384 + d];
#pragma unroll
        for (int rs = 0; rs < 2; ++rs) {
            f32x4 az = rs ? acc1[jp] : acc0[jp];
            f32x4 ar = rs ? acc1[4 + jp] : acc0[4 + jp];
            f32x4 axh = rs ? acc1[8 + jp] : acc0[8 + jp];
            f32x4 ahh = rs ? acc1[12 + jp] : acc0[12 + jp];
#pragma unroll
            for (int i = 0; i < 4; ++i) {
                int lr = rt * 32 + rs * 16 + g * 4 + i;
                int gr = r0 + lr;
                if (gr < n) {
                    float h = bf2f(xs[lr][d]);
                    float z = fast_sigmoid(az[i] + bz);
                    float r = fast_sigmoid(ar[i] + brr);
                    float hc = fast_tanh(axh[i] + bxh + r * (ahh[i] + bhh));
                    state[(size_t)gr * 128 + d] = f2bf(z * h + (1.0f - z) * hc);
                }
            }
        }
    }
}

// ---------------------------------------------------------------------------
// readout stages 2+3 (h1 bf16)
// ---------------------------------------------------------------------------
__global__ __launch_bounds__(256) void k_read2(
    const unsigned short* __restrict__ h1,
    const float* __restrict__ W2, const float* __restrict__ b2,
    const float* __restrict__ W3, const float* __restrict__ b3,
    float* __restrict__ out, int n)
{
    __shared__ float W2ls[128][64];
    __shared__ float W3ls[64][16];
    __shared__ float h1ls[8][132];
    __shared__ float h2ls[8][66];
    __shared__ float lgls[8][16];
    int tid = threadIdx.x;
    int r0 = blockIdx.x * 8;

#pragma unroll
    for (int i = 0; i < 8; ++i) {
        int id = i * 256 + tid;
        int kr = id >> 4, c4 = id & 15;
        *(float4*)&W2ls[kr][c4 * 4] = *(const float4*)&W2[kr * 64 + c4 * 4];
    }
    for (int id = tid; id < 960; id += 256) {
        W3ls[id / 15][id % 15] = W3[id];
    }
    {
        int r = tid >> 5, c4 = tid & 31;
        int gr = r0 + r; if (gr >= n) gr = n - 1;
        u16x4 v = *(const u16x4*)&h1[(size_t)gr * 128 + c4 * 4];
#pragma unroll
        for (int k = 0; k < 4; ++k) h1ls[r][c4 * 4 + k] = bf2f(v[k]);
    }
    __syncthreads();

    {
        int row = tid >> 5, c = tid & 31;
        float a0 = b2[c], a1 = b2[c + 32];
        for (int k = 0; k < 128; ++k) {
            float h = h1ls[row][k];
            a0 = fmaf(h, W2ls[k][c], a0);
            a1 = fmaf(h, W2ls[k][c + 32], a1);
        }
        h2ls[row][c] = fmaxf(a0, 0.f);
        h2ls[row][c + 32] = fmaxf(a1, 0.f);
    }
    __syncthreads();

    if (tid < 120) {
        int row = tid / 15, c = tid % 15;
        float a = b3[c];
        for (int k = 0; k < 64; ++k) a = fmaf(h2ls[row][k], W3ls[k][c], a);
        lgls[row][c] = a;
    }
    __syncthreads();

    if (tid < 120) {
        int row = tid / 15, c = tid % 15;
        int gr = r0 + row;
        if (gr < n) {
            float m = -1e30f;
#pragma unroll
            for (int k = 0; k < 15; ++k) m = fmaxf(m, lgls[row][k]);
            float s = 0.f;
#pragma unroll
            for (int k = 0; k < 15; ++k) s += expf(lgls[row][k] - m);
            out[(size_t)gr * 15 + c] = expf(lgls[row][c] - m) / s;
        }
    }
}

// ---------------------------------------------------------------------------
extern "C" void kernel_launch(void* const* d_in, const int* in_sizes, int n_in,
                              void* d_out, int out_size, void* d_ws, size_t ws_size,
                              hipStream_t stream) {
    const float* feat   = (const float*)d_in[0];
    const int*   src_ip = (const int*)d_in[1];
    const int*   dst_ip = (const int*)d_in[2];
    const int*   src_cn = (const int*)d_in[3];
    const int*   dst_cn = (const int*)d_in[4];
    const float* Wm1 = (const float*)d_in[7];
    const float* bm1 = (const float*)d_in[8];
    const float* Wm2 = (const float*)d_in[9];
    const float* bm2 = (const float*)d_in[10];
    const float* k_ip  = (const float*)d_in[11];
    const float* rk_ip = (const float*)d_in[12];
    const float* bi_ip = (const float*)d_in[13];
    const float* br_ip = (const float*)d_in[14];
    const float* k_cn  = (const float*)d_in[15];
    const float* rk_cn = (const float*)d_in[16];
    const float* bi_cn = (const float*)d_in[17];
    const float* br_cn = (const float*)d_in[18];
    const float* Wr1 = (const float*)d_in[19];
    const float* br1 = (const float*)d_in[20];
    const float* Wr2 = (const float*)d_in[21];
    const float* br2 = (const float*)d_in[22];
    const float* Wr3 = (const float*)d_in[23];
    const float* br3 = (const float*)d_in[24];

    const int n_e = in_sizes[1];
    const int n_c = in_sizes[0] / FEAT;
    const int n_i = 50000;

    auto align = [](size_t x) { return (x + 255) & ~(size_t)255; };
    char* ws = (char*)d_ws;
    size_t off = 0;
    unsigned short* ip_state   = (unsigned short*)(ws + off); off = align(off + (size_t)n_i * D * 2);
    unsigned short* conn_state = (unsigned short*)(ws + off); off = align(off + (size_t)n_c * D * 2);
    unsigned short* PQ_ip = (unsigned short*)(ws + off); off = align(off + (size_t)n_i * 256 * 2);
    unsigned short* PQ_cn = (unsigned short*)(ws + off); off = align(off + (size_t)n_c * 256 * 2);
    unsigned short* h1buf = (unsigned short*)(ws + off); off = align(off + (size_t)n_c * 128 * 2);
    short* WGpq_ip    = (short*)(ws + off); off = align(off + (size_t)4 * 16 * 512 * 2);
    short* WGpq_cn    = (short*)(ws + off); off = align(off + (size_t)4 * 16 * 512 * 2);
    short* WGg_ip     = (short*)(ws + off); off = align(off + (size_t)8 * 24 * 512 * 2);
    short* WGg_cn     = (short*)(ws + off); off = align(off + (size_t)8 * 24 * 512 * 2);
    short* WGr1       = (short*)(ws + off); off = align(off + (size_t)4 * 8 * 512 * 2);
    float* cb_ip      = (float*)(ws + off); off = align(off + (size_t)512 * 4);
    float* cb_cn      = (float*)(ws + off); off = align(off + (size_t)512 * 4);
    int*   zb         = (int*)(ws + off);   off = align(off + (size_t)(2 * n_c + 2 * n_i) * 4);
    int*   cnt_c      = zb;
    int*   cnt_i      = zb + n_c;
    int*   cursor_c   = zb + n_c + n_i;
    int*   cursor_i   = zb + 2 * n_c + n_i;
    int*   off_c      = (int*)(ws + off);   off = align(off + (size_t)n_c * 4);
    int*   off_i      = (int*)(ws + off);   off = align(off + (size_t)n_i * 4);
    int*   elist_c    = (int*)(ws + off);   off = align(off + (size_t)n_e * 4);
    int*   elist_i    = (int*)(ws + off);   off = align(off + (size_t)n_e * 4);
    int*   bsum_c     = (int*)(ws + off);   off = align(off + (size_t)64 * 4);
    int*   bsum_i     = (int*)(ws + off);   off = align(off + (size_t)64 * 4);

    // ---- init states (bf16, fused) ----
    int init_total = n_i * D + n_c * D;
    k_init_dual<<<(init_total + 255) / 256, 256, 0, stream>>>(
        ip_state, conn_state, feat, n_i * D, init_total);

    // ---- weight prep (RTN bf16, direct packs) ----
    k_pack_pq_dual<<<(4 * 16 * 512 + 255) / 256, 256, 0, stream>>>(
        Wm1, Wm2, WGpq_ip, WGpq_cn);
    {
        int nbg = (8 * 24 * 512 + 255) / 256;
        k_pack_gru_dual<<<2 * nbg, 256, 0, stream>>>(
            k_ip, rk_ip, WGg_ip, k_cn, rk_cn, WGg_cn, nbg);
    }
    k_pack_r1<<<(4 * 8 * 512 + 255) / 256, 256, 0, stream>>>(Wr1, WGr1);
    k_gbias_dual<<<2, 128, 0, stream>>>(bi_ip, br_ip, cb_ip, bi_cn, br_cn, cb_cn);

    // ---- CSR build (dual-ized) ----
    hipMemsetAsync(zb, 0, (size_t)(2 * n_c + 2 * n_i) * 4, stream);
    k_counts<<<(n_e + 255) / 256, 256, 0, stream>>>(dst_ip, dst_cn, cnt_c, cnt_i, n_e);
    int nb_c = (n_c + 2047) / 2048, nb_i = (n_i + 2047) / 2048;
    k_scan1_dual<<<nb_c + nb_i, 256, 0, stream>>>(
        cnt_c, off_c, bsum_c, n_c, nb_c, cnt_i, off_i, bsum_i, n_i);
    k_scan2_dual<<<2, 256, 0, stream>>>(bsum_c, nb_c, bsum_i, nb_i);
    k_scan3_dual<<<(n_c + n_i + 255) / 256, 256, 0, stream>>>(
        off_c, bsum_c, n_c, off_i, bsum_i, n_i);
    {
        int nb_e = (n_e + 255) / 256;
        k_scatter_dual<<<2 * nb_e, 256, 0, stream>>>(
            dst_ip, src_ip, off_c, cursor_c, elist_c,
            dst_cn, src_cn, off_i, cursor_i, elist_i, n_e, nb_e);
    }

    int b64_i = (n_i + 63) / 64;
    int b64_c = (n_c + 63) / 64;

    for (int t = 0; t < T_STEPS; ++t) {
        k_mgemm9_dual<4, 16, 0, 1><<<b64_i + b64_c, 256, 0, stream>>>(
            ip_state, conn_state, 128, WGpq_ip, WGpq_cn, nullptr,
            PQ_ip, PQ_cn, 256, b64_i, n_i, n_c);
        // fused agg+GRU: ip gathers P2 (PQ_cn), conn gathers P1 (PQ_ip)
        k_gru12_dual<<<b64_i + b64_c, 256, 0, stream>>>(
            PQ_cn, PQ_ip + 128, elist_i, off_i, cnt_i, bm2, ip_state, WGg_ip, cb_ip,
            PQ_ip, PQ_cn + 128, elist_c, off_c, cnt_c, bm1, conn_state, WGg_cn, cb_cn,
            b64_i, n_i, n_c);
    }

    // readout (bf16 A, bf16 h1)
    k_mgemm9_dual<4, 8, 1, 1><<<b64_c, 256, 0, stream>>>(
        conn_state, conn_state, 128, WGr1, WGr1, br1,
        h1buf, h1buf, 128, b64_c, n_c, n_c);
    k_read2<<<(n_c + 7) / 8, 256, 0, stream>>>(
        h1buf, Wr2, br2, Wr3, br3, (float*)d_out, n_c);
}